// Round 4
// baseline (249.168 us; speedup 1.0000x reference)
//
#include <hip/hip_runtime.h>

// ---------------- constants ----------------
#define NS        4607          // series length: 512 + 4095
#define NTAIL     51            // tail blocks: 0 = GARCH, 1..50 = ACL lag k
#define RBLK      2048          // recon blocks
#define TPB       4             // tiles (256 px) per recon block
#define N_TOTAL   16777216.0    // 4096*512*8 elements in recon sum

// ws layout (floats):
#define WS_PART   0                     // [0, RBLK)  recon partials
#define WS_GARCH  RBLK                  // garch sum
#define WS_ACL    (RBLK + 1)            // 50 acl r^2 values
#define WS_SCR    (RBLK + 64)           // 51 private series buffers, stride 4672
#define SCR_STRIDE 4672

typedef float vf4 __attribute__((ext_vector_type(4)));

__device__ __forceinline__ float wave_sum(float v) {
    for (int o = 32; o > 0; o >>= 1) v += __shfl_down(v, o);
    return v;
}

// -------- Kernel 1: recon blocks (51..2098) + concurrent tail blocks (0..50) --------
// launch_bounds(256,4): VGPR cap 128 — 24 live vf4 (96) + addressing fits.
__global__ __launch_bounds__(256, 4) void main_kernel(
    const float* __restrict__ x, const float* __restrict__ dec,
    float* __restrict__ ws)
{
    const int tid  = threadIdx.x;
    const int lane = tid & 63;
    const int wv   = tid >> 6;
    __shared__ float s4[4];

    if (blockIdx.x >= NTAIL) {
        // ================= recon: 4 tiles, 3-tile-deep PLAIN burst =================
        // EXPERIMENT (round 4): the {plain-cacheable, genuinely-deep-MLP} cell.
        // r1/r2 "plain is slow" was measured with a collapsed burst (VGPR=36,
        // ~5 loads in flight — invariant-load sinking defeated the barriers).
        // r3 proved the laundering compiles/runs; NT gave ~70us = r0's 72.
        // If plain+deep ~= 50us: L2/L3 path + depth beats the NT ~2.9TB/s wall.
        // If plain+deep ~= 91us: depth is null for plain too -> NT wall is real.
        const int rb = blockIdx.x - NTAIL;
        float acc = 0.f;

        const long long pix0 = (long long)rb * (TPB * 256);
        const char* dbase = (const char*)dec + pix0 * 64;   // 64 B per pixel
        const char* xbase = (const char*)x   + pix0 * 32;   // 32 B per pixel
        // launder: strip kernarg provenance so loads are not "invariant"
        // (otherwise the asm memory barriers below do not bind them)
        asm volatile("" : "+s"(dbase), "+s"(xbase));

        const int  xi = ((tid >> 2) << 1) | (tid & 1);      // x idx for r=0 (dup-pair)
        const bool im = (tid & 3) < 2;                      // q = (tid+256r)&3 = tid&3

        vf4 d00,d01,d02,d03, x00,x01,x02,x03;
        vf4 d10,d11,d12,d13, x10,x11,x12,x13;
        vf4 d20,d21,d22,d23, x20,x21,x22,x23;
        vf4 d30,d31,d32,d33, x30,x31,x32,x33;

#define LOADT(T) do { \
        const vf4* dp = (const vf4*)(dbase + (T)*16384); \
        const vf4* xp = (const vf4*)(xbase + (T)*8192);  \
        d##T##0 = dp[tid];        x##T##0 = xp[xi];       \
        d##T##1 = dp[tid + 256];  x##T##1 = xp[xi + 128]; \
        d##T##2 = dp[tid + 512];  x##T##2 = xp[xi + 256]; \
        d##T##3 = dp[tid + 768];  x##T##3 = xp[xi + 384]; \
    } while (0)

#define COMP(a, xx) do { \
        vf4 b; \
        b.x = __shfl_xor(a.x, 2); b.y = __shfl_xor(a.y, 2); \
        b.z = __shfl_xor(a.z, 2); b.w = __shfl_xor(a.w, 2); \
        float xe0 = im ? xx.x : xx.z; \
        float me0 = im ? a.x  : b.z;  \
        float le0 = im ? b.x  : a.z;  \
        float xe1 = im ? xx.y : xx.w; \
        float me1 = im ? a.y  : b.w;  \
        float le1 = im ? b.y  : a.w;  \
        float d0 = xe0 - me0, d1 = xe1 - me1; \
        acc += le0 + d0 * d0 * __expf(-le0); \
        acc += le1 + d1 * d1 * __expf(-le1); \
    } while (0)

        LOADT(0); LOADT(1); LOADT(2);          // 24 loads in flight (24 KB/wave)
        asm volatile("" ::: "memory");
        COMP(d00,x00); COMP(d01,x01); COMP(d02,x02); COMP(d03,x03);   // vmcnt(16)
        LOADT(3);                              // refill: 8 more while 16 in flight
        asm volatile("" ::: "memory");
        COMP(d10,x10); COMP(d11,x11); COMP(d12,x12); COMP(d13,x13);   // vmcnt(16)
        COMP(d20,x20); COMP(d21,x21); COMP(d22,x22); COMP(d23,x23);   // vmcnt(8)
        COMP(d30,x30); COMP(d31,x31); COMP(d32,x32); COMP(d33,x33);   // vmcnt(0)

#undef LOADT
#undef COMP

        acc = wave_sum(acc);
        if (lane == 0) s4[wv] = acc;
        __syncthreads();
        if (tid == 0) ws[WS_PART + rb] = s4[0] + s4[1] + s4[2] + s4[3];
    } else {
        // ============ tail block: private global scratch (no big LDS) ============
        const float OMEGA = 0.05f, ALPHA = 0.1f, BETA = 0.85f;
        float* scr = ws + WS_SCR + blockIdx.x * SCR_STRIDE;

        // gather series from dec (strided; hidden under recon), raw -> scratch
        float lsum = 0.f;
        for (int j = tid; j < NS; j += 256) {
            float v = (j < 512) ? dec[(long long)j * 16]
                                : dec[(long long)(j - 511) * 8192 + 8176];
            scr[j] = v;
            lsum += v;
        }
        lsum = wave_sum(lsum);
        __syncthreads();
        if (lane == 0) s4[wv] = lsum;
        __syncthreads();
        const float mean = (s4[0] + s4[1] + s4[2] + s4[3]) / (float)NS;

        // center in scratch + variance
        float vsum = 0.f;
        __syncthreads();
        for (int j = tid; j < NS; j += 256) {
            float v = scr[j] - mean;
            scr[j] = v;
            vsum += v * v;
        }
        vsum = wave_sum(vsum);
        __syncthreads();
        if (lane == 0) s4[wv] = vsum;
        __syncthreads();
        const float var = s4[0] + s4[1] + s4[2] + s4[3];

        if (blockIdx.x == 0) {
            // ---- GARCH: chunked scan, shfl compose (segment: x_out = p*x_in + e) ----
            const int start = tid * 18;
            const int end   = min(start + 18, NS);
            float e = 0.f, p = 1.f;
            for (int i = start; i < end; ++i) {
                float r2 = scr[i] * scr[i];
                e = (OMEGA + ALPHA * r2) + BETA * e;
                p *= BETA;
            }
            for (int o = 1; o < 64; o <<= 1) {          // wave inclusive scan
                float pe = __shfl_up(e, o), pp = __shfl_up(p, o);
                if (lane >= o) { e = e + p * pe; p = p * pp; }
            }
            __shared__ float wE[4], wP[4];
            if (lane == 63) { wE[wv] = e; wP[wv] = p; }
            __syncthreads();
            float cE = 0.f, cP = 1.f;
            for (int t = 0; t < wv; ++t) { cE = wE[t] + wP[t] * cE; cP = wP[t] * cP; }
            float eE = __shfl_up(e, 1), eP = __shfl_up(p, 1);
            if (lane == 0) { eE = 0.f; eP = 1.f; }
            float prev = (eE + eP * cE) + (eP * cP) * 1.0f;   // sigma0 = 1.0
            float g = 0.f;
            for (int i = start; i < end; ++i) {
                float r2 = scr[i] * scr[i];
                float cv = OMEGA + ALPHA * r2 + BETA * prev;
                prev = cv;
                g += 0.5f * logf(0.5f * cv) + 2.5f * log1pf(r2 / (2.f * cv));
            }
            g = wave_sum(g);
            __syncthreads();
            if (lane == 0) s4[wv] = g;
            __syncthreads();
            if (tid == 0) ws[WS_GARCH] = s4[0] + s4[1] + s4[2] + s4[3];
        } else {
            // ---- ACL lag k ----
            const int k = blockIdx.x;   // 1..50
            float a = 0.f;
            for (int i = tid; i < NS - k; i += 256) a += scr[i] * scr[i + k];
            a = wave_sum(a);
            __syncthreads();
            if (lane == 0) s4[wv] = a;
            __syncthreads();
            if (tid == 0) {
                float r = (s4[0] + s4[1] + s4[2] + s4[3]) / var;
                ws[WS_ACL + (k - 1)] = r * r;
            }
        }
    }
}

// -------- Kernel 2: final combine (dispatch boundary provides coherence) --------
__global__ __launch_bounds__(256) void final_kernel(
    const float* __restrict__ ws, float* __restrict__ out)
{
    const int tid  = threadIdx.x;
    const int lane = tid & 63;
    const int wv   = tid >> 6;
    __shared__ double d4[4];
    __shared__ float  aclbuf[1];

    double ds = 0.0;
    for (int i = tid; i < RBLK; i += 256) ds += (double)ws[WS_PART + i];
    for (int o = 32; o > 0; o >>= 1) ds += __shfl_down(ds, o);
    if (lane == 0) d4[wv] = ds;

    if (wv == 0) {
        float av = (lane < 50) ? ws[WS_ACL + lane] : 0.f;
        av = wave_sum(av);
        if (lane == 0) aclbuf[0] = av;
    }
    __syncthreads();

    if (tid == 0) {
        const double LOG_2PI = 1.8378770664093453;
        const double NEG_C   = 0.9808292530117262; // -(gammaln(2.5)-gammaln(2)-0.5*log(4*pi))
        double q = d4[0] + d4[1] + d4[2] + d4[3];
        double recon = 0.5 * (q + N_TOTAL * LOG_2PI) / 4096.0;
        double acl   = (double)aclbuf[0] / 50.0;
        double garch = (double)ws[WS_GARCH] + (double)NS * NEG_C;
        out[0] = (float)(recon + 10.0 * acl + 0.001 * garch);
    }
}

extern "C" void kernel_launch(void* const* d_in, const int* in_sizes, int n_in,
                              void* d_out, int out_size, void* d_ws, size_t ws_size,
                              hipStream_t stream) {
    const float* x_true  = (const float*)d_in[0];   // 4096*512*8
    const float* dec_out = (const float*)d_in[1];   // 4096*512*16
    float* ws  = (float*)d_ws;
    float* out = (float*)d_out;

    main_kernel<<<RBLK + NTAIL, 256, 0, stream>>>(x_true, dec_out, ws);
    final_kernel<<<1, 256, 0, stream>>>(ws, out);
}

// Round 5
// 229.143 us; speedup vs baseline: 1.0874x; 1.0874x over previous
//
#include <hip/hip_runtime.h>

// ---------------- constants ----------------
#define NS        4607          // series length: 512 + 4095
#define NTAIL     51            // tail blocks: 0 = GARCH, 1..50 = ACL lag k
#define RBLK      2048          // recon blocks
#define TPB       4             // tiles (256 px) per recon block
#define N_TOTAL   16777216.0    // 4096*512*8 elements in recon sum

// ws layout (floats):
#define WS_PART   0                     // [0, RBLK)  recon partials
#define WS_GARCH  RBLK                  // garch sum
#define WS_ACL    (RBLK + 1)            // 50 acl r^2 values
#define WS_SCR    (RBLK + 64)           // 51 private series buffers, stride 4672
#define SCR_STRIDE 4672

typedef float vf4 __attribute__((ext_vector_type(4)));

__device__ __forceinline__ float wave_sum(float v) {
    for (int o = 32; o > 0; o >>= 1) v += __shfl_down(v, o);
    return v;
}

// -------- Kernel 1: recon blocks (51..2098) + concurrent tail blocks (0..50) --------
// launch_bounds(256,4): VGPR cap 128 — 64 data + 16 addr + misc ≈ 98 fits.
__global__ __launch_bounds__(256, 4) void main_kernel(
    const float* __restrict__ x, const float* __restrict__ dec,
    float* __restrict__ ws)
{
    const int tid  = threadIdx.x;
    const int lane = tid & 63;
    const int wv   = tid >> 6;
    __shared__ float s4[4];

    if (blockIdx.x >= NTAIL) {
        // ============ recon: inline-asm NT burst, counted-vmcnt pipeline ============
        // Rounds 1/2/4 proved the compiler ALWAYS collapses C-level load bursts
        // (VGPR=36, ~5 in flight, invariant-load sinking past asm barriers).
        // This version forces the schedule in the ISA: volatile inline-asm
        // global_load_dwordx4 (mutually ordered, cannot be collapsed) with a
        // 2-tile rotating register buffer: 16 loads in flight, drain 8 / refill
        // 8 per tile via explicit s_waitcnt vmcnt(8). sched_barrier(0) after
        // each waitcnt is MANDATORY: the compiler does not track vmcnt for
        // asm-produced values and would otherwise hoist reads above the wait.
        // NT flag kept: pure 201MB stream; plain-cacheable measured 91 vs 72.
        const int rb = blockIdx.x - NTAIL;
        float acc = 0.f;

        const long long pix0 = (long long)rb * (TPB * 256);
        const char* dbase = (const char*)dec + pix0 * 64;   // 64 B per pixel
        const char* xbase = (const char*)x   + pix0 * 32;   // 32 B per pixel
        const int  xi = ((tid >> 2) << 1) | (tid & 1);      // x idx (dup-pair)
        const bool im = (tid & 3) < 2;                      // q = tid&3

        // per-lane addresses, advanced by one tile (16KB / 8KB) after each burst
        const vf4* dp0 = (const vf4*)dbase + tid;
        const vf4* dp1 = dp0 + 256;
        const vf4* dp2 = dp0 + 512;
        const vf4* dp3 = dp0 + 768;
        const vf4* xp0 = (const vf4*)xbase + xi;
        const vf4* xp1 = xp0 + 128;
        const vf4* xp2 = xp0 + 256;
        const vf4* xp3 = xp0 + 384;

        vf4 dA0,dA1,dA2,dA3, xA0,xA1,xA2,xA3;   // buffer A (tiles 0,2)
        vf4 dB0,dB1,dB2,dB3, xB0,xB1,xB2,xB3;   // buffer B (tiles 1,3)

#define GL(dst, p) \
        asm volatile("global_load_dwordx4 %0, %1, off nt" : "=v"(dst) : "v"(p))

        // issue exactly 8 VMEM ops, then advance pointers one tile
#define LOADT(S) do { \
        GL(d##S##0, dp0); GL(x##S##0, xp0); \
        GL(d##S##1, dp1); GL(x##S##1, xp1); \
        GL(d##S##2, dp2); GL(x##S##2, xp2); \
        GL(d##S##3, dp3); GL(x##S##3, xp3); \
        dp0 += 1024; dp1 += 1024; dp2 += 1024; dp3 += 1024; \
        xp0 += 512;  xp1 += 512;  xp2 += 512;  xp3 += 512;  \
    } while (0)

#define WAITV(N) do { \
        asm volatile("s_waitcnt vmcnt(" #N ")" ::: "memory"); \
        __builtin_amdgcn_sched_barrier(0); \
    } while (0)

#define COMP(a, xx) do { \
        vf4 b; \
        b.x = __shfl_xor(a.x, 2); b.y = __shfl_xor(a.y, 2); \
        b.z = __shfl_xor(a.z, 2); b.w = __shfl_xor(a.w, 2); \
        float xe0 = im ? xx.x : xx.z; \
        float me0 = im ? a.x  : b.z;  \
        float le0 = im ? b.x  : a.z;  \
        float xe1 = im ? xx.y : xx.w; \
        float me1 = im ? a.y  : b.w;  \
        float le1 = im ? b.y  : a.w;  \
        float d0 = xe0 - me0, d1 = xe1 - me1; \
        acc += le0 + d0 * d0 * __expf(-le0); \
        acc += le1 + d1 * d1 * __expf(-le1); \
    } while (0)

        LOADT(A);                       // tile 0 in flight (8)
        LOADT(B);                       // tile 1 in flight (16)
        WAITV(8);                       // tile 0 landed
        COMP(dA0,xA0); COMP(dA1,xA1); COMP(dA2,xA2); COMP(dA3,xA3);
        LOADT(A);                       // tile 2 -> buffer A (16 in flight)
        WAITV(8);                       // tile 1 landed
        COMP(dB0,xB0); COMP(dB1,xB1); COMP(dB2,xB2); COMP(dB3,xB3);
        LOADT(B);                       // tile 3 -> buffer B (16 in flight)
        WAITV(8);                       // tile 2 landed
        COMP(dA0,xA0); COMP(dA1,xA1); COMP(dA2,xA2); COMP(dA3,xA3);
        WAITV(0);                       // tile 3 landed
        COMP(dB0,xB0); COMP(dB1,xB1); COMP(dB2,xB2); COMP(dB3,xB3);

#undef GL
#undef LOADT
#undef WAITV
#undef COMP

        acc = wave_sum(acc);
        if (lane == 0) s4[wv] = acc;
        __syncthreads();
        if (tid == 0) ws[WS_PART + rb] = s4[0] + s4[1] + s4[2] + s4[3];
    } else {
        // ============ tail block: private global scratch (no big LDS) ============
        const float OMEGA = 0.05f, ALPHA = 0.1f, BETA = 0.85f;
        float* scr = ws + WS_SCR + blockIdx.x * SCR_STRIDE;

        // gather series from dec (strided; hidden under recon), raw -> scratch
        float lsum = 0.f;
        for (int j = tid; j < NS; j += 256) {
            float v = (j < 512) ? dec[(long long)j * 16]
                                : dec[(long long)(j - 511) * 8192 + 8176];
            scr[j] = v;
            lsum += v;
        }
        lsum = wave_sum(lsum);
        __syncthreads();
        if (lane == 0) s4[wv] = lsum;
        __syncthreads();
        const float mean = (s4[0] + s4[1] + s4[2] + s4[3]) / (float)NS;

        // center in scratch + variance
        float vsum = 0.f;
        __syncthreads();
        for (int j = tid; j < NS; j += 256) {
            float v = scr[j] - mean;
            scr[j] = v;
            vsum += v * v;
        }
        vsum = wave_sum(vsum);
        __syncthreads();
        if (lane == 0) s4[wv] = vsum;
        __syncthreads();
        const float var = s4[0] + s4[1] + s4[2] + s4[3];

        if (blockIdx.x == 0) {
            // ---- GARCH: chunked scan, shfl compose (segment: x_out = p*x_in + e) ----
            const int start = tid * 18;
            const int end   = min(start + 18, NS);
            float e = 0.f, p = 1.f;
            for (int i = start; i < end; ++i) {
                float r2 = scr[i] * scr[i];
                e = (OMEGA + ALPHA * r2) + BETA * e;
                p *= BETA;
            }
            for (int o = 1; o < 64; o <<= 1) {          // wave inclusive scan
                float pe = __shfl_up(e, o), pp = __shfl_up(p, o);
                if (lane >= o) { e = e + p * pe; p = p * pp; }
            }
            __shared__ float wE[4], wP[4];
            if (lane == 63) { wE[wv] = e; wP[wv] = p; }
            __syncthreads();
            float cE = 0.f, cP = 1.f;
            for (int t = 0; t < wv; ++t) { cE = wE[t] + wP[t] * cE; cP = wP[t] * cP; }
            float eE = __shfl_up(e, 1), eP = __shfl_up(p, 1);
            if (lane == 0) { eE = 0.f; eP = 1.f; }
            float prev = (eE + eP * cE) + (eP * cP) * 1.0f;   // sigma0 = 1.0
            float g = 0.f;
            for (int i = start; i < end; ++i) {
                float r2 = scr[i] * scr[i];
                float cv = OMEGA + ALPHA * r2 + BETA * prev;
                prev = cv;
                g += 0.5f * logf(0.5f * cv) + 2.5f * log1pf(r2 / (2.f * cv));
            }
            g = wave_sum(g);
            __syncthreads();
            if (lane == 0) s4[wv] = g;
            __syncthreads();
            if (tid == 0) ws[WS_GARCH] = s4[0] + s4[1] + s4[2] + s4[3];
        } else {
            // ---- ACL lag k ----
            const int k = blockIdx.x;   // 1..50
            float a = 0.f;
            for (int i = tid; i < NS - k; i += 256) a += scr[i] * scr[i + k];
            a = wave_sum(a);
            __syncthreads();
            if (lane == 0) s4[wv] = a;
            __syncthreads();
            if (tid == 0) {
                float r = (s4[0] + s4[1] + s4[2] + s4[3]) / var;
                ws[WS_ACL + (k - 1)] = r * r;
            }
        }
    }
}

// -------- Kernel 2: final combine (dispatch boundary provides coherence) --------
__global__ __launch_bounds__(256) void final_kernel(
    const float* __restrict__ ws, float* __restrict__ out)
{
    const int tid  = threadIdx.x;
    const int lane = tid & 63;
    const int wv   = tid >> 6;
    __shared__ double d4[4];
    __shared__ float  aclbuf[1];

    double ds = 0.0;
    for (int i = tid; i < RBLK; i += 256) ds += (double)ws[WS_PART + i];
    for (int o = 32; o > 0; o >>= 1) ds += __shfl_down(ds, o);
    if (lane == 0) d4[wv] = ds;

    if (wv == 0) {
        float av = (lane < 50) ? ws[WS_ACL + lane] : 0.f;
        av = wave_sum(av);
        if (lane == 0) aclbuf[0] = av;
    }
    __syncthreads();

    if (tid == 0) {
        const double LOG_2PI = 1.8378770664093453;
        const double NEG_C   = 0.9808292530117262; // -(gammaln(2.5)-gammaln(2)-0.5*log(4*pi))
        double q = d4[0] + d4[1] + d4[2] + d4[3];
        double recon = 0.5 * (q + N_TOTAL * LOG_2PI) / 4096.0;
        double acl   = (double)aclbuf[0] / 50.0;
        double garch = (double)ws[WS_GARCH] + (double)NS * NEG_C;
        out[0] = (float)(recon + 10.0 * acl + 0.001 * garch);
    }
}

extern "C" void kernel_launch(void* const* d_in, const int* in_sizes, int n_in,
                              void* d_out, int out_size, void* d_ws, size_t ws_size,
                              hipStream_t stream) {
    const float* x_true  = (const float*)d_in[0];   // 4096*512*8
    const float* dec_out = (const float*)d_in[1];   // 4096*512*16
    float* ws  = (float*)d_ws;
    float* out = (float*)d_out;

    main_kernel<<<RBLK + NTAIL, 256, 0, stream>>>(x_true, dec_out, ws);
    final_kernel<<<1, 256, 0, stream>>>(ws, out);
}